// Round 5
// baseline (265.482 us; speedup 1.0000x reference)
//
#include <hip/hip_runtime.h>
#include <math.h>

typedef unsigned int u32;
typedef unsigned long long u64;
typedef _Float16 f16;
typedef f16 half8v __attribute__((ext_vector_type(8)));
typedef float f32x4 __attribute__((ext_vector_type(4)));

#define Bc 128
#define Dc 1024
#define Hc 131072
#define Oc 1024
#define Rc 512

#define NBINS 4096
#define NSUB 2
#define CAP 6144

// ws layout in 4-byte units
#define WS_SCORES ((size_t)0)
#define WS_SEL    ((size_t)Bc * Hc)
#define WS_PART   (WS_SEL + (size_t)Bc * Rc)
#define WS_XHI    (WS_PART + (size_t)Bc * 4 * Oc)         // x hi split, 131072 f16
#define WS_XLO    (WS_XHI + (size_t)Bc * Dc / 2)          // x lo split

__device__ __forceinline__ u32 mono_key(float f) {
    u32 u = __float_as_uint(f);
    return (u & 0x80000000u) ? ~u : (u | 0x80000000u);
}

__device__ __forceinline__ void dma16(const f16* gsrc, const f16* ldst) {
    __builtin_amdgcn_global_load_lds(
        (const __attribute__((address_space(1))) unsigned int*)(const void*)gsrc,
        (__attribute__((address_space(3))) unsigned int*)(const void*)ldst, 16, 0, 0);
}

// ---------------- K0: split x into f16 hi + scaled-lo, pre-swizzled ----------------
// Elem (row, k): stored at kt*4096 + row*32 + ((kslot ^ (row&3))<<3) + (k&7),
// kt = k>>5, kslot = (k>>3)&3. k1's DMA copies each 4096-elem kt-block verbatim.
__global__ __launch_bounds__(512) void kx_split(const float* __restrict__ x,
                                                f16* __restrict__ xhi,
                                                f16* __restrict__ xlo) {
    int c = blockIdx.x * 512 + threadIdx.x;   // 0..16383 chunks of 8
    int row = c >> 7;                         // 0..127
    int kc = c & 127;                         // k-chunk
    const float* src = x + (size_t)row * Dc + kc * 8;
    float4 v0 = *reinterpret_cast<const float4*>(src);
    float4 v1 = *reinterpret_cast<const float4*>(src + 4);
    int kt = kc >> 2;
    int kslot = kc & 3;
    int dst = kt * 4096 + row * 32 + ((kslot ^ (row & 3)) << 3);
    half8v h, l;
#pragma unroll
    for (int e = 0; e < 8; ++e) {
        float f = (e < 4) ? reinterpret_cast<const float*>(&v0)[e]
                          : reinterpret_cast<const float*>(&v1)[e - 4];
        f16 hh = (f16)f;
        h[e] = hh;
        l[e] = (f16)((f - (float)hh) * 2048.0f);
    }
    *reinterpret_cast<half8v*>(xhi + dst) = h;
    *reinterpret_cast<half8v*>(xlo + dst) = l;
}

// ---------------- K1: S = x @ Win^T via f16 split MFMA ----------------
// 128x128 tile, BK=32, 256 threads = 4 waves (2m x 2n), wave = 64x64 out.
// A via global_load_lds DMA (pre-split f16), B reg-staged + converted.
// 64 KB LDS dbuf -> 2 independent blocks/CU for barrier-drain cover.
#define AHI 0
#define ALO 4096
#define BHI 8192
#define BLO 12288
__global__ __launch_bounds__(256, 2) void k1_mfma(const float* __restrict__ Win,
                                                  const f16* __restrict__ xhi,
                                                  const f16* __restrict__ xlo,
                                                  float* __restrict__ S) {
    __shared__ f16 lds[2][16384];   // 64 KB: [buf][Ahi|Alo|Bhi|Blo]
    const int tid = threadIdx.x;
    const int h0 = blockIdx.x * 128;

    // B staging: thread -> (col = tid>>1, khalf = tid&1), 16 consecutive k (64 B)
    const int bcol = tid >> 1;
    const int bkh = tid & 1;
    const float* bsrc = Win + (size_t)(h0 + bcol) * Dc + bkh * 16;
    const int bs0 = bcol * 32 + (((bkh * 2 + 0) ^ (bcol & 3)) << 3);
    const int bs1 = bcol * 32 + (((bkh * 2 + 1) ^ (bcol & 3)) << 3);

    const int lane = tid & 63;
    const int wid = tid >> 6;
    const int wm = wid >> 1;                // 0..1
    const int wn = wid & 1;                 // 0..1
    const int lr = lane & 15;
    const int lk = lane >> 4;               // k-slot for fragment reads
    const int dmaoff = wid * 512;           // wave-uniform DMA lds offset (elems)

    f32x4 acc1[4][4], acc2[4][4];
#pragma unroll
    for (int i = 0; i < 4; ++i)
#pragma unroll
        for (int j = 0; j < 4; ++j) {
            acc1[i][j] = (f32x4){0.f, 0.f, 0.f, 0.f};
            acc2[i][j] = (f32x4){0.f, 0.f, 0.f, 0.f};
        }

    // prologue: stage ks=0 into buf0
    {
        f16* L = lds[0];
        // A DMA: hi 8KB + lo 8KB, 2 issues each (256 thr x 16 B = 4 KB/issue)
        dma16(xhi + 0 * 4096 + 0 + dmaoff + lane * 8, L + AHI + 0 + dmaoff);
        dma16(xhi + 0 * 4096 + 2048 + dmaoff + lane * 8, L + AHI + 2048 + dmaoff);
        dma16(xlo + 0 * 4096 + 0 + dmaoff + lane * 8, L + ALO + 0 + dmaoff);
        dma16(xlo + 0 * 4096 + 2048 + dmaoff + lane * 8, L + ALO + 2048 + dmaoff);
        // B: load 16 fp32, split, write
        float4 q0 = *reinterpret_cast<const float4*>(bsrc);
        float4 q1 = *reinterpret_cast<const float4*>(bsrc + 4);
        float4 q2 = *reinterpret_cast<const float4*>(bsrc + 8);
        float4 q3 = *reinterpret_cast<const float4*>(bsrc + 12);
        half8v h0, l0, h1, l1;
#pragma unroll
        for (int e = 0; e < 8; ++e) {
            float fa = reinterpret_cast<const float*>(&q0)[e < 4 ? e : -1];
            (void)fa;
        }
#pragma unroll
        for (int e = 0; e < 4; ++e) {
            float f;
            f = reinterpret_cast<const float*>(&q0)[e];
            { f16 hh = (f16)f; h0[e] = hh; l0[e] = (f16)((f - (float)hh) * 2048.0f); }
            f = reinterpret_cast<const float*>(&q1)[e];
            { f16 hh = (f16)f; h0[e + 4] = hh; l0[e + 4] = (f16)((f - (float)hh) * 2048.0f); }
            f = reinterpret_cast<const float*>(&q2)[e];
            { f16 hh = (f16)f; h1[e] = hh; l1[e] = (f16)((f - (float)hh) * 2048.0f); }
            f = reinterpret_cast<const float*>(&q3)[e];
            { f16 hh = (f16)f; h1[e + 4] = hh; l1[e + 4] = (f16)((f - (float)hh) * 2048.0f); }
        }
        *reinterpret_cast<half8v*>(L + BHI + bs0) = h0;
        *reinterpret_cast<half8v*>(L + BLO + bs0) = l0;
        *reinterpret_cast<half8v*>(L + BHI + bs1) = h1;
        *reinterpret_cast<half8v*>(L + BLO + bs1) = l1;
    }
    __syncthreads();

    for (int ks = 0; ks < 32; ++ks) {
        f16* C = lds[ks & 1];
        f16* N = lds[(ks & 1) ^ 1];
        const bool pf = (ks < 31);
        float4 q0, q1, q2, q3;
        if (pf) {
            // issue next-tile loads early: B to regs, A via DMA into alt buffer
            const float* bs = bsrc + (ks + 1) * 32;
            q0 = *reinterpret_cast<const float4*>(bs);
            q1 = *reinterpret_cast<const float4*>(bs + 4);
            q2 = *reinterpret_cast<const float4*>(bs + 8);
            q3 = *reinterpret_cast<const float4*>(bs + 12);
            const f16* xh = xhi + (ks + 1) * 4096;
            const f16* xl = xlo + (ks + 1) * 4096;
            dma16(xh + 0 + dmaoff + lane * 8, N + AHI + 0 + dmaoff);
            dma16(xh + 2048 + dmaoff + lane * 8, N + AHI + 2048 + dmaoff);
            dma16(xl + 0 + dmaoff + lane * 8, N + ALO + 0 + dmaoff);
            dma16(xl + 2048 + dmaoff + lane * 8, N + ALO + 2048 + dmaoff);
        }
        // fragments + MFMA from current buffer
        half8v afh[4], afl[4];
#pragma unroll
        for (int i = 0; i < 4; ++i) {
            int r = wm * 64 + i * 16 + lr;
            int ad = r * 32 + ((lk ^ (r & 3)) << 3);
            afh[i] = *reinterpret_cast<const half8v*>(C + AHI + ad);
            afl[i] = *reinterpret_cast<const half8v*>(C + ALO + ad);
        }
#pragma unroll
        for (int j = 0; j < 4; ++j) {
            int cdx = wn * 64 + j * 16 + lr;
            int bd = cdx * 32 + ((lk ^ (cdx & 3)) << 3);
            half8v bfh = *reinterpret_cast<const half8v*>(C + BHI + bd);
            half8v bfl = *reinterpret_cast<const half8v*>(C + BLO + bd);
#pragma unroll
            for (int i = 0; i < 4; ++i) {
                acc1[i][j] = __builtin_amdgcn_mfma_f32_16x16x32_f16(afh[i], bfh, acc1[i][j], 0, 0, 0);
                acc2[i][j] = __builtin_amdgcn_mfma_f32_16x16x32_f16(afh[i], bfl, acc2[i][j], 0, 0, 0);
                acc2[i][j] = __builtin_amdgcn_mfma_f32_16x16x32_f16(afl[i], bfh, acc2[i][j], 0, 0, 0);
            }
        }
        // convert + write next B tile, single barrier
        if (pf) {
            half8v h0, l0, h1, l1;
#pragma unroll
            for (int e = 0; e < 4; ++e) {
                float f;
                f = reinterpret_cast<const float*>(&q0)[e];
                { f16 hh = (f16)f; h0[e] = hh; l0[e] = (f16)((f - (float)hh) * 2048.0f); }
                f = reinterpret_cast<const float*>(&q1)[e];
                { f16 hh = (f16)f; h0[e + 4] = hh; l0[e + 4] = (f16)((f - (float)hh) * 2048.0f); }
                f = reinterpret_cast<const float*>(&q2)[e];
                { f16 hh = (f16)f; h1[e] = hh; l1[e] = (f16)((f - (float)hh) * 2048.0f); }
                f = reinterpret_cast<const float*>(&q3)[e];
                { f16 hh = (f16)f; h1[e + 4] = hh; l1[e + 4] = (f16)((f - (float)hh) * 2048.0f); }
            }
            *reinterpret_cast<half8v*>(N + BHI + bs0) = h0;
            *reinterpret_cast<half8v*>(N + BLO + bs0) = l0;
            *reinterpret_cast<half8v*>(N + BHI + bs1) = h1;
            *reinterpret_cast<half8v*>(N + BLO + bs1) = l1;
        }
        __syncthreads();
    }
    // epilogue: C/D layout col=lane&15, row=(lane>>4)*4+r  [m89-verified]
#pragma unroll
    for (int i = 0; i < 4; ++i)
#pragma unroll
        for (int j = 0; j < 4; ++j)
#pragma unroll
            for (int r = 0; r < 4; ++r) {
                int row = wm * 64 + i * 16 + lk * 4 + r;
                int col = h0 + wn * 64 + j * 16 + lr;
                S[(size_t)row * Hc + col] = acc1[i][j][r] + acc2[i][j][r] * (1.0f / 2048.0f);
            }
}

// ---------------- K2: fused hist + threshold + select (one block per row) ----------------
#define K2_LDS_BYTES ((NSUB * NBINS) * 4 + Rc * 8 + CAP * 8)
__global__ __launch_bounds__(1024) void k2_select(const float* __restrict__ S,
                                                  u32* __restrict__ selidx) {
    extern __shared__ u32 dyn[];
    u32* lh  = dyn;                               // NSUB*NBINS
    u64* top = (u64*)(dyn + NSUB * NBINS);        // 512
    u64* cand = (u64*)(dyn + NSUB * NBINS + Rc * 2);  // CAP
    __shared__ u32 csum[64];
    __shared__ u32 s_bint, s_need, cnt_top, cnt_cand;

    const int b = blockIdx.x;
    const int tid = threadIdx.x;
    for (int i = tid; i < NSUB * NBINS; i += 1024) lh[i] = 0;
    if (tid == 0) { cnt_top = 0; cnt_cand = 0; }
    __syncthreads();

    const float4* row4 = reinterpret_cast<const float4*>(S + (size_t)b * Hc);
    const int sub = (tid & (NSUB - 1)) * NBINS;
    for (int it = 0; it < Hc / 4096; ++it) {
        float4 v = row4[tid + it * 1024];
#pragma unroll
        for (int e = 0; e < 4; ++e) {
            u32 bin = mono_key(reinterpret_cast<const float*>(&v)[e]) >> 20;
            atomicAdd(&lh[sub + bin], 1u);
        }
    }
    __syncthreads();
    for (int i = tid; i < NBINS; i += 1024) lh[i] += lh[NBINS + i];
    __syncthreads();
    if (tid < 64) {
        u32 s = 0;
        for (int j = 0; j < 64; ++j) s += lh[tid * 64 + j];
        csum[tid] = s;
    }
    __syncthreads();
    if (tid == 0) {
        u32 cum = 0;
        int c;
        for (c = 63; c >= 0; --c) {
            if (cum + csum[c] >= (u32)Rc) break;
            cum += csum[c];
        }
        int bin_t = 0; u32 above = 0;
        for (int j = 63; j >= 0; --j) {
            int bin = c * 64 + j;
            if (cum + lh[bin] >= (u32)Rc) { bin_t = bin; above = cum; break; }
            cum += lh[bin];
        }
        s_bint = (u32)bin_t;
        s_need = (u32)Rc - above;
    }
    __syncthreads();
    const u32 bin_t = s_bint;
    const u32 need  = s_need;
    for (int it = 0; it < Hc / 4096; ++it) {
        float4 v = row4[tid + it * 1024];
        int i0 = (tid + it * 1024) * 4;
#pragma unroll
        for (int e = 0; e < 4; ++e) {
            u32 u = mono_key(reinterpret_cast<const float*>(&v)[e]);
            u32 bin = u >> 20;
            if (bin > bin_t) {
                u32 p = atomicAdd(&cnt_top, 1u);
                top[p] = ((u64)u << 32) | (u64)(0xFFFFFFFFu - (u32)(i0 + e));
            } else if (bin == bin_t) {
                u32 p = atomicAdd(&cnt_cand, 1u);
                if (p < CAP) cand[p] = ((u64)u << 32) | (u64)(0xFFFFFFFFu - (u32)(i0 + e));
            }
        }
    }
    __syncthreads();
    const int ntop = (int)cnt_top;
    const int nc   = (int)(cnt_cand < (u32)CAP ? cnt_cand : (u32)CAP);
    u32* sel = selidx + (size_t)b * Rc;
    for (int j = tid; j < ntop; j += 1024) {
        u64 my = top[j];
        u32 r = 0;
        for (int k = 0; k < ntop; ++k) r += (top[k] > my) ? 1u : 0u;
        sel[r] = 0xFFFFFFFFu - (u32)(my & 0xFFFFFFFFu);
    }
    for (int j = tid; j < nc; j += 1024) {
        u64 my = cand[j];
        u32 r = 0;
        for (int k = 0; k < nc; ++k) r += (cand[k] > my) ? 1u : 0u;
        if (r < need) sel[ntop + r] = 0xFFFFFFFFu - (u32)(my & 0xFFFFFFFFu);
    }
}

// ---------------- K3: partial[b][ch][o] = sum over 128 selected rows ----------------
__global__ __launch_bounds__(256) void k3_gather(const float* __restrict__ S,
                                                 const float* __restrict__ Wout,
                                                 const u32* __restrict__ selidx,
                                                 float* __restrict__ part) {
    __shared__ float g[128];
    __shared__ u32 il[128];
    const int b  = blockIdx.x >> 2;
    const int ch = blockIdx.x & 3;
    const int tid = threadIdx.x;
    if (tid < 128) {
        u32 idx = selidx[(size_t)b * Rc + ch * 128 + tid];
        il[tid] = idx;
        float s = S[(size_t)b * Hc + idx];
        g[tid] = 0.5f * s * (1.0f + erff(s * 0.70710678118654752f));
    }
    __syncthreads();
    float4 acc = make_float4(0.f, 0.f, 0.f, 0.f);
    const int o0 = tid * 4;
#pragma unroll 4
    for (int j = 0; j < 128; ++j) {
        float w = g[j];
        float4 v = *reinterpret_cast<const float4*>(&Wout[(size_t)il[j] * Oc + o0]);
        acc.x = fmaf(w, v.x, acc.x);
        acc.y = fmaf(w, v.y, acc.y);
        acc.z = fmaf(w, v.z, acc.z);
        acc.w = fmaf(w, v.w, acc.w);
    }
    *reinterpret_cast<float4*>(&part[((size_t)b * 4 + ch) * Oc + o0]) = acc;
}

// ---------------- K4: reduce 4 partials -> out ----------------
__global__ __launch_bounds__(256) void k4_reduce(const float* __restrict__ part,
                                                 float* __restrict__ out) {
    const int b = blockIdx.x;
    const int o0 = threadIdx.x * 4;
    float4 a = *reinterpret_cast<const float4*>(&part[((size_t)b * 4 + 0) * Oc + o0]);
    float4 c1 = *reinterpret_cast<const float4*>(&part[((size_t)b * 4 + 1) * Oc + o0]);
    float4 c2 = *reinterpret_cast<const float4*>(&part[((size_t)b * 4 + 2) * Oc + o0]);
    float4 c3 = *reinterpret_cast<const float4*>(&part[((size_t)b * 4 + 3) * Oc + o0]);
    a.x += c1.x + c2.x + c3.x;
    a.y += c1.y + c2.y + c3.y;
    a.z += c1.z + c2.z + c3.z;
    a.w += c1.w + c2.w + c3.w;
    *reinterpret_cast<float4*>(&out[(size_t)b * Oc + o0]) = a;
}

extern "C" void kernel_launch(void* const* d_in, const int* in_sizes, int n_in,
                              void* d_out, int out_size, void* d_ws, size_t ws_size,
                              hipStream_t stream) {
    (void)in_sizes; (void)n_in; (void)out_size; (void)ws_size;
    const float* x    = (const float*)d_in[0];
    const float* Win  = (const float*)d_in[1];
    const float* Wout = (const float*)d_in[2];
    float* out = (float*)d_out;

    float* S    = (float*)d_ws + WS_SCORES;
    u32*   sel  = (u32*)d_ws + WS_SEL;
    float* part = (float*)d_ws + WS_PART;
    f16*   xhi  = (f16*)((u32*)d_ws + WS_XHI);
    f16*   xlo  = (f16*)((u32*)d_ws + WS_XLO);

    static bool attr_set = false;
    if (!attr_set) {
        hipFuncSetAttribute((const void*)k2_select,
                            hipFuncAttributeMaxDynamicSharedMemorySize, K2_LDS_BYTES);
        attr_set = true;
    }

    kx_split<<<32, 512, 0, stream>>>(x, xhi, xlo);
    k1_mfma<<<Hc / 128, 256, 0, stream>>>(Win, xhi, xlo, S);
    k2_select<<<Bc, 1024, K2_LDS_BYTES, stream>>>(S, sel);
    k3_gather<<<Bc * 4, 256, 0, stream>>>(S, Wout, sel, part);
    k4_reduce<<<Bc, 256, 0, stream>>>(part, out);
}